// Round 5
// baseline (3428.021 us; speedup 1.0000x reference)
//
#include <hip/hip_runtime.h>

#define T_LEN   512
#define H_DIM   128
#define OUT_DIM 7
#define TC      8                 // timesteps per chunk
#define NCHUNK  (T_LEN / TC)      // 64
#define BB      2                 // batch rows per block
#define NBLK    256               // 1 block/CU
#define NTHREADS 512              // 8 waves

typedef __bf16 bf16x8 __attribute__((ext_vector_type(8)));
typedef float  f32x4  __attribute__((ext_vector_type(4)));

// Gate-row permutation: MFMA row P <-> original W row
//   orig(P) = 128*(P&3)*? -- decomposed: P = 16*mt + u, mt = w + 8*i, u in [0,16)
//   orig = 128*(u&3) + 32*i + 4*w + (u>>2)
// => output acc[i][r] (lane q,n16) = gate r (i,f,g,o) of j = 4*w + 32*i + q, col n16 = batch.
__device__ __forceinline__ int orig_row(int P) {
  const int mt = P >> 4, u = P & 15;
  return ((u & 3) << 7) + ((mt >> 3) << 5) + ((mt & 7) << 2) + (u >> 2);
}

struct __align__(16) SharedMem {
  float  xg[TC][2][129][4];  // [s][b][j(+pad)][gate]; wave-private in j -> no barrier
  float  g2[2][128][4];      // [b][j][gate] step handoff
  float  z[2][H_DIM];        // fc1 out
  __bf16 h[2][2][H_DIM];     // [parity][b][j]
  __bf16 hist[TC][2][H_DIM]; // chunk h history -> batched global store
};

__device__ __forceinline__ float sigf(float x) {
  return __builtin_amdgcn_rcpf(1.f + __expf(-x));
}
__device__ __forceinline__ float tanh_fast(float x) {
  x = fminf(fmaxf(x, -15.f), 15.f);
  float e = __expf(2.f * x);
  return (e - 1.f) * __builtin_amdgcn_rcpf(e + 1.f);
}
__device__ __forceinline__ bf16x8 load8_f32_bf16(const float* p) {
  const f32x4 a = *(const f32x4*)p;
  const f32x4 b = *(const f32x4*)(p + 4);
  bf16x8 r;
  #pragma unroll
  for (int j = 0; j < 4; ++j) { r[j] = (__bf16)a[j]; r[4 + j] = (__bf16)b[j]; }
  return r;
}
__device__ __forceinline__ bf16x8 zero_bf16x8() {
  bf16x8 r;
  #pragma unroll
  for (int j = 0; j < 8; ++j) r[j] = (__bf16)0.f;
  return r;
}

__global__ __launch_bounds__(NTHREADS, 2)   // 8 waves/block, 1 block/CU, <=256 VGPR
void lstm_kernel(const float* __restrict__ x,
                 const float* __restrict__ wih0, const float* __restrict__ whh0,
                 const float* __restrict__ bih0, const float* __restrict__ bhh0,
                 const float* __restrict__ wih1, const float* __restrict__ whh1,
                 const float* __restrict__ bih1, const float* __restrict__ bhh1,
                 const float* __restrict__ wih2, const float* __restrict__ whh2,
                 const float* __restrict__ bih2, const float* __restrict__ bhh2,
                 const float* __restrict__ fc1w, const float* __restrict__ fc1b,
                 const float* __restrict__ fc2w, const float* __restrict__ fc2b,
                 float* __restrict__ out, __bf16* __restrict__ buf)
{
  __shared__ SharedMem sh;
  const int tid = threadIdx.x;
  const int w   = tid >> 6;    // wave 0..7
  const int l   = tid & 63;
  const int q   = l >> 4;
  const int n16 = l & 15;
  const int bg  = blockIdx.x * BB;
  const int j0  = 4 * w + q;   // wave/lane j base; tile i -> j = j0 + 32*i

  const float* WIH[3] = {wih0, wih1, wih2};
  const float* WHH[3] = {whh0, whh1, whh2};
  const float* BIH[3] = {bih0, bih1, bih2};
  const float* BHH[3] = {bhh0, bhh1, bhh2};

  for (int lyr = 0; lyr < 3; ++lyr) {
    const float* w_ih = WIH[lyr];
    const float* w_hh = WHH[lyr];
    const int kin        = (lyr == 0) ? 8 : H_DIM;
    const int kin_chunks = (lyr == 0) ? 1 : 4;

    // ---- resident A-frags (permuted rows) + bias C-init, once per layer ----
    bf16x8 whhf[4][4], wihf[4][4];
    f32x4  biasv[4];
    #pragma unroll
    for (int i = 0; i < 4; ++i) {
      const int P  = 16 * (w + 8 * i) + n16;
      const int ro = orig_row(P);
      #pragma unroll
      for (int kc = 0; kc < 4; ++kc) {
        whhf[i][kc] = load8_f32_bf16(w_hh + ro * H_DIM + kc * 32 + q * 8);
        const int k0 = kc * 32 + q * 8;
        wihf[i][kc] = (k0 < kin) ? load8_f32_bf16(w_ih + ro * kin + k0)
                                 : zero_bf16x8();
      }
      const int jj = j0 + 32 * i;
      f32x4 bv;
      #pragma unroll
      for (int r = 0; r < 4; ++r)
        bv[r] = BIH[lyr][(r << 7) + jj] + BHH[lyr][(r << 7) + jj];
      biasv[i] = bv;
    }
    if (tid < 2 * H_DIM) (&sh.h[0][0][0])[tid] = (__bf16)0.f;  // parity 0 for t=0
    float c_st = 0.f;      // cell state for threads tid<256: (b=tid>>7, j=tid&127)
    __syncthreads();       // h reset visible; drains prev-layer buf stores

    bf16x8 pre[4];         // prologue B-frags, prefetched a chunk ahead
    auto load_pre = [&](int c) {
      const int b = n16 & 1, trel = n16 >> 1;   // col n16 = (step, batch)
      const int t = c * TC + trel;
      if (lyr == 0) {
        pre[0] = zero_bf16x8();
        if (q == 0) pre[0] = load8_f32_bf16(x + ((size_t)(bg + b) * T_LEN + t) * 8);
      } else {
        #pragma unroll
        for (int kc = 0; kc < 4; ++kc)
          pre[kc] = *(const bf16x8*)(buf + ((size_t)(bg + b) * T_LEN + t) * H_DIM
                                         + kc * 32 + q * 8);
      }
    };
    load_pre(0);

    f32x4 cin[4];          // next step's C-init (xg), wave-private prefetch

    for (int c0 = 0; c0 < NCHUNK; ++c0) {
      const int t0 = c0 * TC;

      // ---- chunk epilogue of previous chunk: batched hist -> buf ----
      if (lyr < 2 && c0 > 0 && tid < 256) {
        const int s2 = tid >> 5, rem = tid & 31;
        const int b2 = rem >> 4, k8 = (rem & 15) * 8;
        const bf16x8 v = *(const bf16x8*)&sh.hist[s2][b2][k8];
        *(bf16x8*)(buf + ((size_t)(bg + b2) * T_LEN + (t0 - TC) + s2) * H_DIM + k8) = v;
      }

      // ---- prologue (no barrier needed: xg is wave-private in j) ----
      {
        f32x4 acc[4];
        #pragma unroll
        for (int i = 0; i < 4; ++i) acc[i] = biasv[i];
        for (int kc = 0; kc < kin_chunks; ++kc) {   // wave-uniform
          #pragma unroll
          for (int i = 0; i < 4; ++i)
            acc[i] = __builtin_amdgcn_mfma_f32_16x16x32_bf16(wihf[i][kc], pre[kc], acc[i], 0, 0, 0);
        }
        #pragma unroll
        for (int i = 0; i < 4; ++i)
          *(f32x4*)&sh.xg[n16 >> 1][n16 & 1][j0 + 32 * i][0] = acc[i];
      }
      if (c0 + 1 < NCHUNK) load_pre(c0 + 1);
      #pragma unroll
      for (int i = 0; i < 4; ++i)            // cin for s=0 (wave-local, DS in-order)
        cin[i] = *(const f32x4*)&sh.xg[0][n16 & 1][j0 + 32 * i][0];

      // ---- TC steps, exactly 2 barriers each ----
      for (int s = 0; s < TC; ++s) {
        const int cur = s & 1, nxt = cur ^ 1;   // t parity == s parity (TC even)

        f32x4 acc[4];
        #pragma unroll
        for (int i = 0; i < 4; ++i) acc[i] = cin[i];
        #pragma unroll
        for (int kc = 0; kc < 4; ++kc) {
          const bf16x8 bfrag = *(const bf16x8*)&sh.h[cur][n16 & 1][kc * 32 + q * 8];
          #pragma unroll
          for (int i = 0; i < 4; ++i)
            acc[i] = __builtin_amdgcn_mfma_f32_16x16x32_bf16(whhf[i][kc], bfrag, acc[i], 0, 0, 0);
        }
        if (n16 < 2) {                      // cols 0,1 = real batch rows
          #pragma unroll
          for (int i = 0; i < 4; ++i)
            *(f32x4*)&sh.g2[n16][j0 + 32 * i][0] = acc[i];
        }
        if (s + 1 < TC) {                   // wave-private xg prefetch, off critical path
          #pragma unroll
          for (int i = 0; i < 4; ++i)
            cin[i] = *(const f32x4*)&sh.xg[s + 1][n16 & 1][j0 + 32 * i][0];
        }
        __syncthreads();

        if (tid < 2 * H_DIM) {              // dense gate phase: waves 0-3, 1 elem/thread
          const int b = tid >> 7, j = tid & 127;
          const f32x4 g = *(const f32x4*)&sh.g2[b][j][0];
          c_st = sigf(g[1]) * c_st + sigf(g[0]) * tanh_fast(g[2]);
          const __bf16 hb = (__bf16)(sigf(g[3]) * tanh_fast(c_st));
          sh.h[nxt][b][j]  = hb;
          sh.hist[s][b][j] = hb;
        }
        __syncthreads();
      }
    }

    // ---- final chunk's hist -> buf ----
    if (lyr < 2 && tid < 256) {
      const int s2 = tid >> 5, rem = tid & 31;
      const int b2 = rem >> 4, k8 = (rem & 15) * 8;
      const bf16x8 v = *(const bf16x8*)&sh.hist[s2][b2][k8];
      *(bf16x8*)(buf + ((size_t)(bg + b2) * T_LEN + (T_LEN - TC) + s2) * H_DIM + k8) = v;
    }
  }

  // ---- FC head: final h (t=511 -> parity 0) ----
  if (tid < 2 * H_DIM) {
    const int b = tid >> 7, i = tid & 127;
    float a = fc1b[i];
    const float* wr = fc1w + i * H_DIM;
    #pragma unroll 8
    for (int k = 0; k < H_DIM; ++k)
      a += (float)sh.h[0][b][k] * wr[k];
    sh.z[b][i] = fmaxf(a, 0.f);
  }
  __syncthreads();
  if (tid < BB * OUT_DIM) {
    const int b = tid / OUT_DIM, o = tid % OUT_DIM;
    float a = fc2b[o];
    for (int k = 0; k < H_DIM; ++k)
      a += sh.z[b][k] * fc2w[o * H_DIM + k];
    out[(size_t)(bg + b) * OUT_DIM + o] = a;
  }
}

extern "C" void kernel_launch(void* const* d_in, const int* in_sizes, int n_in,
                              void* d_out, int out_size, void* d_ws, size_t ws_size,
                              hipStream_t stream) {
  const float* x    = (const float*)d_in[0];
  const float* wih0 = (const float*)d_in[1];
  const float* whh0 = (const float*)d_in[2];
  const float* bih0 = (const float*)d_in[3];
  const float* bhh0 = (const float*)d_in[4];
  const float* wih1 = (const float*)d_in[5];
  const float* whh1 = (const float*)d_in[6];
  const float* bih1 = (const float*)d_in[7];
  const float* bhh1 = (const float*)d_in[8];
  const float* wih2 = (const float*)d_in[9];
  const float* whh2 = (const float*)d_in[10];
  const float* bih2 = (const float*)d_in[11];
  const float* bhh2 = (const float*)d_in[12];
  const float* fc1w = (const float*)d_in[13];
  const float* fc1b = (const float*)d_in[14];
  const float* fc2w = (const float*)d_in[15];
  const float* fc2b = (const float*)d_in[16];
  float* out  = (float*)d_out;
  __bf16* buf = (__bf16*)d_ws;   // [512][512][128] bf16 = 64 MiB inter-layer buffer

  lstm_kernel<<<dim3(NBLK), dim3(NTHREADS), 0, stream>>>(
      x, wih0, whh0, bih0, bhh0, wih1, whh1, bih1, bhh1,
      wih2, whh2, bih2, bhh2, fc1w, fc1b, fc2w, fc2b, out, buf);
}

// Round 6
// 1345.560 us; speedup vs baseline: 2.5477x; 2.5477x over previous
//
#include <hip/hip_runtime.h>

#define B_TOT   512
#define T_LEN   512
#define F_IN_D  8
#define H_DIM   128
#define OUT_DIM 7
#define TC      8                 // timesteps per chunk (xg prologue granularity)
#define NCHUNK  (T_LEN / TC)      // 64
#define BB      2                 // batch rows per block
#define NBLK    (B_TOT / BB)      // 256 blocks -> 1 per CU
#define NTHREADS 512              // 8 waves

typedef __bf16 bf16x8 __attribute__((ext_vector_type(8)));
typedef __bf16 bf16x4 __attribute__((ext_vector_type(4)));
typedef float  f32x4  __attribute__((ext_vector_type(4)));

struct __align__(16) SharedMem {
  float  xg[2 * TC][520];    // [2*trel + b][gate]  (row = n16 in prologue store)
  float  g[2][520];          // [b][gate] raw gate pre-activations for one step
  float  z[2][H_DIM];        // fc1 output
  __bf16 h[2][2][160];       // [parity][b][k]; stride 160 elems -> b=1 is +16 banks
  __bf16 hist[TC][2][H_DIM]; // chunk h history -> ONE coalesced global store per chunk
};

__device__ __forceinline__ float sigf(float x) {
  return __builtin_amdgcn_rcpf(1.f + __expf(-x));
}
__device__ __forceinline__ float tanh_fast(float x) {
  x = fminf(fmaxf(x, -15.f), 15.f);
  float e = __expf(2.f * x);
  return (e - 1.f) * __builtin_amdgcn_rcpf(e + 1.f);
}
__device__ __forceinline__ bf16x8 load8_f32_bf16(const float* p) {
  const f32x4 a = *(const f32x4*)p;
  const f32x4 b = *(const f32x4*)(p + 4);
  bf16x8 r;
  #pragma unroll
  for (int j = 0; j < 4; ++j) { r[j] = (__bf16)a[j]; r[4 + j] = (__bf16)b[j]; }
  return r;
}
__device__ __forceinline__ bf16x8 zero_bf16x8() {
  bf16x8 r;
  #pragma unroll
  for (int j = 0; j < 8; ++j) r[j] = (__bf16)0.f;
  return r;
}

// R1 structure: one block owns batch rows [2*bid, 2*bid+2) through all layers.
// MFMA: M=gate(512, 32 tiles), N=batch(cols 0,1 valid), K=128.
// Wave w owns tiles {w, w+8, w+16, w+24} = gates (i,f,g,o) for h rows [16w,16w+16).
// Per step: MFMA phase (8 waves) -> barrier -> gate phase (4 waves, 1 elem/thread)
// -> barrier. Delta vs R1: h store goes to LDS hist; global flush once per chunk.
__global__ __launch_bounds__(NTHREADS, 2)
void lstm_kernel(const float* __restrict__ x,
                 const float* __restrict__ wih0, const float* __restrict__ whh0,
                 const float* __restrict__ bih0, const float* __restrict__ bhh0,
                 const float* __restrict__ wih1, const float* __restrict__ whh1,
                 const float* __restrict__ bih1, const float* __restrict__ bhh1,
                 const float* __restrict__ wih2, const float* __restrict__ whh2,
                 const float* __restrict__ bih2, const float* __restrict__ bhh2,
                 const float* __restrict__ fc1w, const float* __restrict__ fc1b,
                 const float* __restrict__ fc2w, const float* __restrict__ fc2b,
                 float* __restrict__ out, __bf16* __restrict__ buf)
{
  __shared__ SharedMem sh;
  const int tid = threadIdx.x;
  const int w   = tid >> 6;   // wave 0..7
  const int l   = tid & 63;   // lane
  const int q   = l >> 4;     // quad 0..3
  const int n16 = l & 15;     // MFMA col / row-within-tile
  const int bg  = blockIdx.x * BB;

  const float* WIH[3] = {wih0, wih1, wih2};
  const float* WHH[3] = {whh0, whh1, whh2};
  const float* BIH[3] = {bih0, bih1, bih2};
  const float* BHH[3] = {bhh0, bhh1, bhh2};

  for (int lyr = 0; lyr < 3; ++lyr) {
    const float* w_ih = WIH[lyr];
    const float* w_hh = WHH[lyr];
    const float* b_ih = BIH[lyr];
    const float* b_hh = BHH[lyr];
    const int kin        = (lyr == 0) ? F_IN_D : H_DIM;
    const int kin_chunks = (lyr == 0) ? 1 : 4;

    // ---- per-layer resident A-fragments (weights) + bias C-init ----
    bf16x8 whhf[4][4];   // [tile][kchunk]
    bf16x8 wihf[4][4];
    f32x4  biasv[4];
    #pragma unroll
    for (int i = 0; i < 4; ++i) {
      const int mt  = w + 8 * i;            // tile index
      const int row = 16 * mt + n16;        // A row m = lane&15
      #pragma unroll
      for (int kc = 0; kc < 4; ++kc) {
        whhf[i][kc] = load8_f32_bf16(w_hh + row * H_DIM + kc * 32 + q * 8);
        const int k0 = kc * 32 + q * 8;
        wihf[i][kc] = (k0 < kin) ? load8_f32_bf16(w_ih + row * kin + k0)
                                 : zero_bf16x8();
      }
      const int gidx = 16 * mt + 4 * q;     // C/D row = quad*4+r
      f32x4 bv;
      #pragma unroll
      for (int r = 0; r < 4; ++r) bv[r] = b_ih[gidx + r] + b_hh[gidx + r];
      biasv[i] = bv;
    }

    // ---- reset recurrent state (h parity 0 read by t=0) ----
    if (tid < 2 * H_DIM) sh.h[0][tid >> 7][tid & 127] = (__bf16)0.f;
    float c_st = 0.f;   // cell state for thread tid<256: (b=tid>>7, j=tid&127)
    __syncthreads();    // also drains previous layer's hist flush (vmcnt)

    for (int c0 = 0; c0 < NCHUNK; ++c0) {
      const int t0 = c0 * TC;

      // ---- flush previous chunk's hist -> buf (coalesced; drains under prologue) ----
      if (lyr < 2 && c0 > 0 && tid < 256) {
        const int s2 = tid >> 5, rem = tid & 31;
        const int b2 = rem >> 4, k8 = (rem & 15) * 8;
        const bf16x8 v = *(const bf16x8*)&sh.hist[s2][b2][k8];
        *(bf16x8*)(buf + ((size_t)(bg + b2) * T_LEN + (t0 - TC) + s2) * H_DIM + k8) = v;
      }

      // ---- chunk prologue: xg for TC steps, N = time*batch = 16 (full tile) ----
      {
        f32x4 acc[4];
        #pragma unroll
        for (int i = 0; i < 4; ++i) acc[i] = biasv[i];
        const int bb   = n16 & 1;
        const int trel = n16 >> 1;
        const int t    = t0 + trel;
        #pragma unroll
        for (int kc = 0; kc < 4; ++kc) {
          if (kc < kin_chunks) {            // wave-uniform guard
            bf16x8 bfrag;
            if (lyr == 0) {
              bfrag = zero_bf16x8();
              if (q == 0)                   // k = q*8+j < 8 only in quad 0
                bfrag = load8_f32_bf16(x + ((size_t)(bg + bb) * T_LEN + t) * F_IN_D);
            } else {
              bfrag = *(const bf16x8*)(buf + ((size_t)(bg + bb) * T_LEN + t) * H_DIM
                                           + kc * 32 + q * 8);
            }
            #pragma unroll
            for (int i = 0; i < 4; ++i)
              acc[i] = __builtin_amdgcn_mfma_f32_16x16x32_bf16(
                  wihf[i][kc], bfrag, acc[i], 0, 0, 0);
          }
        }
        #pragma unroll
        for (int i = 0; i < 4; ++i)
          *(f32x4*)&sh.xg[n16][16 * (w + 8 * i) + 4 * q] = acc[i];
      }
      __syncthreads();

      // ---- TC recurrence steps (identical to R1 except h store -> hist) ----
      for (int s = 0; s < TC; ++s) {
        const int t   = t0 + s;
        const int cur = t & 1;
        const int nxt = cur ^ 1;

        f32x4 acc[4];
        #pragma unroll
        for (int i = 0; i < 4; ++i)   // C-init = xg(+bias); cols>=2 read b&1 (broadcast)
          acc[i] = *(const f32x4*)&sh.xg[2 * s + (l & 1)][16 * (w + 8 * i) + 4 * q];
        #pragma unroll
        for (int kc = 0; kc < 4; ++kc) {
          // B[k][n] = h[n&1][k]; dead cols replicate row 0/1 -> free broadcast
          bf16x8 bfrag = *(const bf16x8*)&sh.h[cur][n16 & 1][kc * 32 + q * 8];
          #pragma unroll
          for (int i = 0; i < 4; ++i)
            acc[i] = __builtin_amdgcn_mfma_f32_16x16x32_bf16(
                whhf[i][kc], bfrag, acc[i], 0, 0, 0);
        }
        if (n16 < 2) {                 // only cols 0,1 hold real batch rows
          #pragma unroll
          for (int i = 0; i < 4; ++i)
            *(f32x4*)&sh.g[n16][16 * (w + 8 * i) + 4 * q] = acc[i];
        }
        __syncthreads();

        // compacted gate math: 256 threads, one h-element each
        if (tid < 2 * H_DIM) {
          const int bb = tid >> 7, j = tid & 127;
          const float gi = sh.g[bb][j];
          const float gf = sh.g[bb][H_DIM + j];
          const float gg = sh.g[bb][2 * H_DIM + j];
          const float go = sh.g[bb][3 * H_DIM + j];
          c_st = sigf(gf) * c_st + sigf(gi) * tanh_fast(gg);
          const float hval = sigf(go) * tanh_fast(c_st);
          const __bf16 hb = (__bf16)hval;
          sh.h[nxt][bb][j]  = hb;        // broadcast for t+1
          sh.hist[s][bb][j] = hb;        // batched flush next chunk (NO global store here)
        }
        __syncthreads();
      }
    }

    // ---- flush the last chunk of this layer ----
    if (lyr < 2 && tid < 256) {
      const int s2 = tid >> 5, rem = tid & 31;
      const int b2 = rem >> 4, k8 = (rem & 15) * 8;
      const bf16x8 v = *(const bf16x8*)&sh.hist[s2][b2][k8];
      *(bf16x8*)(buf + ((size_t)(bg + b2) * T_LEN + (T_LEN - TC) + s2) * H_DIM + k8) = v;
    }
  }

  // ---- FC head: final h of layer 2 (t=511 wrote parity 0) ----
  if (tid < 2 * H_DIM) {
    const int bb = tid >> 7, i = tid & 127;
    float a = fc1b[i];
    #pragma unroll 8
    for (int k = 0; k < H_DIM; ++k)
      a += (float)sh.h[0][bb][k] * fc1w[i * H_DIM + k];
    sh.z[bb][i] = fmaxf(a, 0.f);
  }
  __syncthreads();
  if (tid < BB * OUT_DIM) {
    const int bb = tid / OUT_DIM, o = tid % OUT_DIM;
    float a = fc2b[o];
    for (int k = 0; k < H_DIM; ++k)
      a += sh.z[bb][k] * fc2w[o * H_DIM + k];
    out[(size_t)(bg + bb) * OUT_DIM + o] = a;
  }
}

extern "C" void kernel_launch(void* const* d_in, const int* in_sizes, int n_in,
                              void* d_out, int out_size, void* d_ws, size_t ws_size,
                              hipStream_t stream) {
  const float* x    = (const float*)d_in[0];
  const float* wih0 = (const float*)d_in[1];
  const float* whh0 = (const float*)d_in[2];
  const float* bih0 = (const float*)d_in[3];
  const float* bhh0 = (const float*)d_in[4];
  const float* wih1 = (const float*)d_in[5];
  const float* whh1 = (const float*)d_in[6];
  const float* bih1 = (const float*)d_in[7];
  const float* bhh1 = (const float*)d_in[8];
  const float* wih2 = (const float*)d_in[9];
  const float* whh2 = (const float*)d_in[10];
  const float* bih2 = (const float*)d_in[11];
  const float* bhh2 = (const float*)d_in[12];
  const float* fc1w = (const float*)d_in[13];
  const float* fc1b = (const float*)d_in[14];
  const float* fc2w = (const float*)d_in[15];
  const float* fc2b = (const float*)d_in[16];
  float* out  = (float*)d_out;
  __bf16* buf = (__bf16*)d_ws;   // [512][512][128] bf16 = 64 MiB inter-layer buffer

  lstm_kernel<<<dim3(NBLK), dim3(NTHREADS), 0, stream>>>(
      x, wih0, whh0, bih0, bhh0, wih1, whh1, bih1, bhh1,
      wih2, whh2, bih2, bhh2, fc1w, fc1b, fc2w, fc2b, out, buf);
}